// Round 1
// baseline (61.821 us; speedup 1.0000x reference)
//
#include <hip/hip_runtime.h>

#define D 256
#define W8 2048

// workspace float offsets
#define TCARD_OFF   0                 // 53*256
#define THERO_OFF   13568             // 9*256
#define TACT_OFF    15872             // 9*256
#define TNUMP_OFF   18176             // 10*256
#define WSC_OFF     20736             // 2*256 (transposed [k][d])
#define WBET_OFF    21248             // 9*256
#define WACT_OFF    23552             // 8*256
#define WBL_OFF     25600             // 2*256
#define BPART_OFF   26112             // 4*256 bias partials
#define BIAS_OFF    27136             // 256 final bias
// total 27392 floats = ~107 KB of ws

__device__ __forceinline__ void f4acc(float4& a, const float4 b) {
    a.x += b.x; a.y += b.y; a.z += b.z; a.w += b.w;
}
__device__ __forceinline__ void f4fma(float4& a, float v, const float4 b) {
    a.x += v * b.x; a.y += v * b.y; a.z += v * b.z; a.w += v * b.w;
}

// -------- precompute: fold combine_W into tables & section weights --------

template <int NK>
__device__ void fuse_section(const float* __restrict__ combine_W, int wblk,
                             const float* __restrict__ sw,   // LDS [NK][D]
                             const float* __restrict__ sb,   // LDS [D]
                             float* __restrict__ dstT,       // ws [NK][D]
                             float* __restrict__ bpart,      // ws [D]
                             int d)
{
    float acc[NK];
#pragma unroll
    for (int k = 0; k < NK; ++k) acc[k] = 0.f;
    float accb = 0.f;
    const float* wrow = combine_W + (size_t)d * W8 + wblk * D;
    for (int dd = 0; dd < D; dd += 4) {
        float4 w = *(const float4*)(wrow + dd);
        accb += w.x * sb[dd] + w.y * sb[dd + 1] + w.z * sb[dd + 2] + w.w * sb[dd + 3];
#pragma unroll
        for (int k = 0; k < NK; ++k) {
            const float* s = sw + k * D + dd;
            acc[k] += w.x * s[0] + w.y * s[1] + w.z * s[2] + w.w * s[3];
        }
    }
#pragma unroll
    for (int k = 0; k < NK; ++k) dstT[k * D + d] = acc[k];
    bpart[d] = accb;
}

__global__ __launch_bounds__(256) void fuse_kernel(
    const float* __restrict__ combine_W,
    const float* __restrict__ card_t, const float* __restrict__ hero_t,
    const float* __restrict__ act_t,  const float* __restrict__ nump_t,
    const float* __restrict__ scalar_W, const float* __restrict__ scalar_b,
    const float* __restrict__ blind_W,  const float* __restrict__ blind_b,
    const float* __restrict__ bet_W,    const float* __restrict__ bet_b,
    const float* __restrict__ action_W, const float* __restrict__ action_b,
    float* __restrict__ ws)
{
    __shared__ float sh[10 * D];  // 10 KB
    const int blk = blockIdx.x;
    const int d = threadIdx.x;

    if (blk < 81) {
        // fused embedding-table rows: T[r,d] = sum_k Wblk[d,k] * table[r,k]
        const float* src; int wblk; float* dst;
        if (blk < 53)      { src = card_t + blk * D;        wblk = 0; dst = ws + TCARD_OFF + blk * D; }
        else if (blk < 62) { src = hero_t + (blk - 53) * D; wblk = 1; dst = ws + THERO_OFF + (blk - 53) * D; }
        else if (blk < 71) { src = act_t  + (blk - 62) * D; wblk = 2; dst = ws + TACT_OFF  + (blk - 62) * D; }
        else               { src = nump_t + (blk - 71) * D; wblk = 6; dst = ws + TNUMP_OFF + (blk - 71) * D; }
        sh[d] = src[d];
        __syncthreads();
        const float* wrow = combine_W + (size_t)d * W8 + wblk * D;
        float a0 = 0.f, a1 = 0.f, a2 = 0.f, a3 = 0.f;
#pragma unroll 8
        for (int k = 0; k < D; k += 4) {
            float4 w = *(const float4*)(wrow + k);
            a0 += w.x * sh[k];     a1 += w.y * sh[k + 1];
            a2 += w.z * sh[k + 2]; a3 += w.w * sh[k + 3];
        }
        dst[d] = (a0 + a1) + (a2 + a3);
    } else {
        // fused linear-section weights (stored transposed [k][d]) + bias partials
        const int sec = blk - 81;
        const float* secW; const float* secB; int nk, wblk; float* dstT;
        switch (sec) {
            case 0:  secW = scalar_W; secB = scalar_b; nk = 2; wblk = 3; dstT = ws + WSC_OFF;  break;
            case 1:  secW = bet_W;    secB = bet_b;    nk = 9; wblk = 4; dstT = ws + WBET_OFF; break;
            case 2:  secW = action_W; secB = action_b; nk = 8; wblk = 5; dstT = ws + WACT_OFF; break;
            default: secW = blind_W;  secB = blind_b;  nk = 2; wblk = 7; dstT = ws + WBL_OFF;  break;
        }
        for (int k = 0; k < nk; ++k) sh[k * D + d] = secW[d * nk + k];  // transpose into LDS
        sh[9 * D + d] = secB[d];
        __syncthreads();
        float* bpart = ws + BPART_OFF + sec * D;
        if (nk == 2)      fuse_section<2>(combine_W, wblk, sh, sh + 9 * D, dstT, bpart, d);
        else if (nk == 8) fuse_section<8>(combine_W, wblk, sh, sh + 9 * D, dstT, bpart, d);
        else              fuse_section<9>(combine_W, wblk, sh, sh + 9 * D, dstT, bpart, d);
    }
}

__global__ __launch_bounds__(256) void bias_kernel(const float* __restrict__ combine_b,
                                                   float* __restrict__ ws)
{
    const int d = threadIdx.x;
    ws[BIAS_OFF + d] = combine_b[d]
        + ws[BPART_OFF + 0 * D + d] + ws[BPART_OFF + 1 * D + d]
        + ws[BPART_OFF + 2 * D + d] + ws[BPART_OFF + 3 * D + d];
}

// -------- main: one wave per token, each lane owns 4 consecutive d --------

__global__ __launch_bounds__(256) void embed_kernel(
    const int* __restrict__ cards,  const int* __restrict__ hero,
    const int* __restrict__ acting, const int* __restrict__ nump,
    const float* __restrict__ scalars, const float* __restrict__ blinds,
    const float* __restrict__ bets,    const float* __restrict__ action,
    const float* __restrict__ mask,
    const float* __restrict__ ws, float* __restrict__ out, int ntok)
{
    const int wave = threadIdx.x >> 6;
    const int lane = threadIdx.x & 63;
    const int tok = blockIdx.x * 4 + wave;
    if (tok >= ntok) return;
    const int d0 = lane * 4;

    float4 acc = *(const float4*)(ws + BIAS_OFF + d0);

    // cards: mean of 7 fused-table rows
    {
        const int* cp = cards + tok * 7;
        float4 s = {0.f, 0.f, 0.f, 0.f};
#pragma unroll
        for (int j = 0; j < 7; ++j) {
            f4acc(s, *(const float4*)(ws + TCARD_OFF + cp[j] * D + d0));
        }
        const float inv7 = 1.0f / 7.0f;
        f4fma(acc, inv7, s);
    }
    f4acc(acc, *(const float4*)(ws + THERO_OFF + hero[tok]   * D + d0));
    f4acc(acc, *(const float4*)(ws + TACT_OFF  + acting[tok] * D + d0));
    f4acc(acc, *(const float4*)(ws + TNUMP_OFF + nump[tok]   * D + d0));

    // linear sections via fused transposed weights
    {
        const float* f = scalars + tok * 2;
#pragma unroll
        for (int k = 0; k < 2; ++k)
            f4fma(acc, f[k], *(const float4*)(ws + WSC_OFF + k * D + d0));
    }
    {
        const float* f = bets + tok * 9;
#pragma unroll
        for (int k = 0; k < 9; ++k)
            f4fma(acc, f[k], *(const float4*)(ws + WBET_OFF + k * D + d0));
    }
    {
        const float* f = action + tok * 8;
#pragma unroll
        for (int k = 0; k < 8; ++k)
            f4fma(acc, f[k], *(const float4*)(ws + WACT_OFF + k * D + d0));
    }
    {
        const float* f = blinds + tok * 2;
#pragma unroll
        for (int k = 0; k < 2; ++k)
            f4fma(acc, f[k], *(const float4*)(ws + WBL_OFF + k * D + d0));
    }

    const float m = mask[tok];
    float4 o;
    o.x = acc.x * m; o.y = acc.y * m; o.z = acc.z * m; o.w = acc.w * m;
    *(float4*)(out + (size_t)tok * D + d0) = o;
}

extern "C" void kernel_launch(void* const* d_in, const int* in_sizes, int n_in,
                              void* d_out, int out_size, void* d_ws, size_t ws_size,
                              hipStream_t stream) {
    const int*   cards    = (const int*)d_in[0];
    const int*   hero     = (const int*)d_in[1];
    const int*   acting   = (const int*)d_in[2];
    const int*   nump     = (const int*)d_in[3];
    const float* scalars  = (const float*)d_in[4];
    const float* blinds   = (const float*)d_in[5];
    const float* bets     = (const float*)d_in[6];
    const float* action   = (const float*)d_in[7];
    const float* mask     = (const float*)d_in[8];
    const float* card_t   = (const float*)d_in[9];
    const float* hero_t   = (const float*)d_in[10];
    const float* act_t    = (const float*)d_in[11];
    const float* nump_t   = (const float*)d_in[12];
    const float* scalar_W = (const float*)d_in[13];
    const float* scalar_b = (const float*)d_in[14];
    const float* blind_W  = (const float*)d_in[15];
    const float* blind_b  = (const float*)d_in[16];
    const float* bet_W    = (const float*)d_in[17];
    const float* bet_b    = (const float*)d_in[18];
    const float* action_W = (const float*)d_in[19];
    const float* action_b = (const float*)d_in[20];
    const float* combine_W= (const float*)d_in[21];
    const float* combine_b= (const float*)d_in[22];

    float* ws  = (float*)d_ws;
    float* out = (float*)d_out;
    const int ntok = in_sizes[1];  // B*S (hero_pos flat count)

    hipLaunchKernelGGL(fuse_kernel, dim3(85), dim3(256), 0, stream,
                       combine_W, card_t, hero_t, act_t, nump_t,
                       scalar_W, scalar_b, blind_W, blind_b, bet_W, bet_b,
                       action_W, action_b, ws);
    hipLaunchKernelGGL(bias_kernel, dim3(1), dim3(256), 0, stream, combine_b, ws);
    hipLaunchKernelGGL(embed_kernel, dim3((ntok + 3) / 4), dim3(256), 0, stream,
                       cards, hero, acting, nump, scalars, blinds, bets, action, mask,
                       ws, out, ntok);
}